// Round 9
// baseline (438.533 us; speedup 1.0000x reference)
//
#include <hip/hip_runtime.h>
#include <cstdint>
#include <cstddef>

// ---------------------------------------------------------------------------
// Transformer encoder block, bf16 MFMA implementation.
//   x:[2,4096,768] fp32 (+ fp32 weights) -> out fp32 [2,4096,768]
// R16: R15 + two safe consolidations (hot paths frozen):
//   (1) pack_bias merged into fused_convert as 9 tail blocks (NCONV_V is an
//       exact multiple of 256 -> branch is block-uniform). One fewer launch.
//   (2) FFN1 epilogue gelu: libm erff (~30+ insts, branchy) -> A&S 7.1.26
//       5-term poly + v_exp (~18 insts, abs err 1.5e-7 << bf16 eps).
// attn frozen (R14: issue-saturated, MfmaUtil+VALUBusy ~108%, FETCH at
// unique-data floor). GEMM loops frozen (R15 XCD swizzle verified).
// ---------------------------------------------------------------------------

#define D_MODEL 768
#define N_HEADS 12
#define D_K     64
#define SEQ     4096
#define BATCH   2
#define M_ROWS  (BATCH * SEQ)   // 8192
#define H_FF    3072
#define LDQKV   2304            // packed QKV row pitch

// 0.125 * log2(e): scores come out of MFMA already in log2 domain
#define QSCALE 0.18033688011112042f

typedef __bf16 bf16_t;
typedef __attribute__((ext_vector_type(8))) __bf16 bf16x8;
typedef __attribute__((ext_vector_type(4))) __bf16 bf16x4;
typedef __attribute__((ext_vector_type(2))) __bf16 bf16x2;
typedef __attribute__((ext_vector_type(4))) float  floatx4;
typedef __attribute__((ext_vector_type(4))) short  short4_t;

union bf16x4_cast { bf16x4 h; short4_t s; };

#if __has_builtin(__builtin_amdgcn_exp2f)
#define EXP2F(x) __builtin_amdgcn_exp2f(x)
#else
static __device__ __forceinline__ float EXP2F(float x) {
    float r; asm("v_exp_f32 %0, %1" : "=v"(r) : "v"(x)); return r;
}
#endif

// Abramowitz-Stegun 7.1.26 erf: max abs error 1.5e-7 (4 orders below bf16
// rounding). ~18 VALU vs libm erff's ~30+ with branches.
__device__ __forceinline__ float erf_fast(float x) {
    const float ax = fabsf(x);
    const float t  = 1.0f / fmaf(0.3275911f, ax, 1.0f);
    float y = fmaf(t, 1.061405429f, -1.453152027f);
    y = fmaf(t, y, 1.421413741f);
    y = fmaf(t, y, -0.284496736f);
    y = fmaf(t, y, 0.254829592f);
    y *= t;
    const float e = EXP2F(ax * ax * -1.4426950408889634f);   // exp(-x^2)
    const float r = fmaf(-y, e, 1.0f);
    return copysignf(r, x);
}

__device__ __forceinline__ float gelu_exact(float x) {
    return 0.5f * x * (1.0f + erf_fast(x * 0.70710678118654752f));
}

// async global->LDS, 16B per lane, dest = wave-uniform base + lane*16
#define GLL16(gp, lp)                                                         \
    __builtin_amdgcn_global_load_lds(                                         \
        (const __attribute__((address_space(1))) void*)(gp),                  \
        (__attribute__((address_space(3))) void*)(lp), 16, 0, 0)

// -------------------------------- convert ----------------------------------
#define NX_V  (6291456 / 4)    // x: 8192*768
#define NW_V  (589824 / 4)     // 768*768
#define NF_V  (2359296 / 4)    // 3072*768
#define NCONV_V (NX_V + 4 * NW_V + 2 * NF_V)   // 3,342,336 vec4s (= 13056*256)

__global__ __launch_bounds__(256) void fused_convert_kernel(
    const float* __restrict__ x,  const float* __restrict__ wq,
    const float* __restrict__ wk, const float* __restrict__ wv,
    const float* __restrict__ wo, const float* __restrict__ w1,
    const float* __restrict__ w2, const float* __restrict__ bq,
    const float* __restrict__ bk, const float* __restrict__ bv,
    bf16_t* __restrict__ xb, bf16_t* __restrict__ wqkvb,
    bf16_t* __restrict__ wob, bf16_t* __restrict__ w1b,
    bf16_t* __restrict__ w2b, float* __restrict__ bqkv) {
    const int v = blockIdx.x * 256 + threadIdx.x;
    if (v >= NCONV_V) {               // 9 tail blocks: pack QKV bias (fp32)
        const int i = v - NCONV_V;
        if (i < 768)       bqkv[i] = bq[i] * QSCALE;
        else if (i < 1536) bqkv[i] = bk[i - 768];
        else if (i < 2304) bqkv[i] = bv[i - 1536];
        return;
    }
    const float* src; bf16_t* dst; int off; float scale = 1.0f;
    if (v < NX_V)                    { src = x;  dst = xb;              off = v; }
    else if (v < NX_V + NW_V)        { src = wq; dst = wqkvb;           off = v - NX_V; scale = QSCALE; }
    else if (v < NX_V + 2 * NW_V)    { src = wk; dst = wqkvb + 589824;  off = v - NX_V - NW_V; }
    else if (v < NX_V + 3 * NW_V)    { src = wv; dst = wqkvb + 1179648; off = v - NX_V - 2 * NW_V; }
    else if (v < NX_V + 4 * NW_V)    { src = wo; dst = wob;             off = v - NX_V - 3 * NW_V; }
    else if (v < NX_V + 4 * NW_V + NF_V) { src = w1; dst = w1b;         off = v - NX_V - 4 * NW_V; }
    else                             { src = w2; dst = w2b;             off = v - NX_V - 4 * NW_V - NF_V; }
    floatx4 f = *(const floatx4*)&src[(size_t)off * 4];
    bf16x4 o = bf16x4{(bf16_t)(f[0] * scale), (bf16_t)(f[1] * scale),
                      (bf16_t)(f[2] * scale), (bf16_t)(f[3] * scale)};
    *(bf16x4*)&dst[(size_t)off * 4] = o;
}

// -------------------------------- GEMM -------------------------------------
// C[m,n] = act( sum_k A[m,k]*W[n,k] + bias[n] ).  128xBN tile, BK=64,
// XOR-swizzled LDS (linear GLL16 dest + inverse-swizzled global source col
// + swizzled read slot -- rule #21 involution). Swapped-operand MFMA:
// lane holds C[n..n+3] at one m -> bf16x4 epilogue stores.
// R15: XCD-aware bijective block remap, m-major (verified: -27us total).
template<int BN>   // 128 or 64
__global__ __launch_bounds__(256) void gemm_lds_kernel(
    const bf16_t* __restrict__ A, const bf16_t* __restrict__ W,
    const float* __restrict__ bias, bf16_t* __restrict__ C,
    int M, int N, int K, int act) {

    __shared__ bf16_t As[128 * 64];
    __shared__ bf16_t Bs[BN * 64];

    const int t    = threadIdx.x;
    const int lane = t & 63;
    const int w    = t >> 6;
    const int lrow = lane & 15;
    const int quad = lane >> 4;

    // XCD swizzle: each XCD owns T/8 contiguous logical ids = 8 whole m-rows
    const int T    = (int)(gridDim.x * gridDim.y);
    const int flat = (int)(blockIdx.y * gridDim.x + blockIdx.x);
    const int nid  = (flat & 7) * (T >> 3) + (flat >> 3);
    const int n0   = (nid % (int)gridDim.x) * BN;
    const int m0   = (nid / (int)gridDim.x) * 128;

    constexpr int MI = (BN == 128) ? 4 : 2;
    constexpr int NB = (BN == 128) ? 4 : 2;        // B-tile GLL chunks/wave
    const int wmo = (BN == 128) ? (w >> 1) * 64 : w * 32;
    const int wno = (BN == 128) ? (w & 1) * 64 : 0;

    // staging: chunk = 8 rows x 128B; source k-column pre-swizzled
    const int srow = lane >> 3;                    // row within chunk (0..7)
    const int scol = ((lane & 7) ^ srow) * 8;      // inverse-swizzled k col
    size_t a_g[4];
#pragma unroll
    for (int i = 0; i < 4; ++i)
        a_g[i] = (size_t)(m0 + (w * 4 + i) * 8 + srow) * K + scol;
    size_t b_g[NB];
#pragma unroll
    for (int i = 0; i < NB; ++i)
        b_g[i] = (size_t)(n0 + (w * NB + i) * 8 + srow) * K + scol;

    // fragment-read swizzle: slot = (kk*4+quad) ^ (row&7), row&7 == lrow&7
    const int slot0 = (quad ^ (lrow & 7)) * 8;     // kk=0, in elements
    const int slot1 = slot0 ^ 32;                  // kk=1 (ks+4 -> ^4 slots)

    floatx4 acc[MI][4];
#pragma unroll
    for (int i = 0; i < MI; ++i)
#pragma unroll
        for (int j = 0; j < 4; ++j) acc[i][j] = floatx4{0.f, 0.f, 0.f, 0.f};

    for (int k0 = 0; k0 < K; k0 += 64) {
#pragma unroll
        for (int i = 0; i < 4; ++i)
            GLL16(&A[a_g[i] + k0], &As[(w * 4 + i) * 512]);
#pragma unroll
        for (int i = 0; i < NB; ++i)
            GLL16(&W[b_g[i] + k0], &Bs[(w * NB + i) * 512]);
        __syncthreads();

#pragma unroll
        for (int kk = 0; kk < 2; ++kk) {
            const int off = kk ? slot1 : slot0;
            bf16x8 a[MI], b[4];
#pragma unroll
            for (int i = 0; i < MI; ++i)
                a[i] = *(bf16x8*)&As[(wmo + i * 16 + lrow) * 64 + off];
#pragma unroll
            for (int j = 0; j < 4; ++j)
                b[j] = *(bf16x8*)&Bs[(wno + j * 16 + lrow) * 64 + off];
#pragma unroll
            for (int i = 0; i < MI; ++i)
#pragma unroll
                for (int j = 0; j < 4; ++j)
                    acc[i][j] = __builtin_amdgcn_mfma_f32_16x16x32_bf16(
                        b[j], a[i], acc[i][j], 0, 0, 0);   // C^T fragment
        }
        __syncthreads();
    }

    // epilogue: lane holds n = quad*4+{0..3} at m = lrow (per i,j tile)
#pragma unroll
    for (int i = 0; i < MI; ++i) {
        const int m = m0 + wmo + i * 16 + lrow;
#pragma unroll
        for (int j = 0; j < 4; ++j) {
            const int n = n0 + wno + j * 16 + quad * 4;
            const floatx4 bv = *(const floatx4*)&bias[n];
            float v0 = acc[i][j][0] + bv[0];
            float v1 = acc[i][j][1] + bv[1];
            float v2 = acc[i][j][2] + bv[2];
            float v3 = acc[i][j][3] + bv[3];
            if (act) {
                v0 = gelu_exact(v0); v1 = gelu_exact(v1);
                v2 = gelu_exact(v2); v3 = gelu_exact(v3);
            }
            *(bf16x4*)&C[(size_t)m * N + n] =
                bf16x4{(bf16_t)v0, (bf16_t)v1, (bf16_t)v2, (bf16_t)v3};
        }
    }
}

// ------------------------------ attention ----------------------------------
// Flash-style, fixed-base softmax, deferred row-sum. R8 structure (best
// measured): 2 barriers/tile, reg-staged K+V, prefetch issued right after
// barrier1 so the next barrier's vmcnt drain waits on ~600cyc-old loads.
// R14: 1D grid + bijective XCD swizzle (768 = 8 XCDs x 96): each XCD owns
// 3 complete (b,h) K/V panels -> panel L2-resident on exactly one XCD.
// (Verified: FETCH 104->18.5MB, dur 157->135.8us. FROZEN.)
__global__ __launch_bounds__(256, 3) void attn_kernel(
    const bf16_t* __restrict__ QKV, bf16_t* __restrict__ Ctx) {

    __shared__ bf16_t Ks[64 * 72];        // 9216 B  [key][d] pitch 72
    __shared__ bf16_t Vt[64 * 72];        // 9216 B  [d][key^vsw(d)] pitch 72

    const int t    = threadIdx.x;
    const int lane = t & 63;
    const int w    = t >> 6;
    const int lrow = lane & 15;
    const int quad = lane >> 4;

    // bijective XCD remap: consecutive hardware ids round-robin over XCDs;
    // nid gives XCD k the contiguous range [96k, 96k+96) = 3 whole panels.
    const int nid = ((int)blockIdx.x & 7) * 96 + ((int)blockIdx.x >> 3);
    const int qt  = nid & 31;              // q-tile 0..31
    const int bh  = nid >> 5;              // (b,h) 0..23
    const int b   = bh / N_HEADS;
    const int h   = bh % N_HEADS;
    const int q0  = qt * 128 + w * 32;
    const size_t base_q = ((size_t)b * SEQ) * LDQKV + h * D_K;
    const size_t base_k = base_q + 768;
    const size_t base_v = base_q + 1536;
    const size_t base_o = ((size_t)b * SEQ) * D_MODEL + h * D_K;

    // Q fragments (B operand of S^T = K*Q^T: n=q=lane&15, k=d).
    bf16x8 qf[2][2];
#pragma unroll
    for (int s = 0; s < 2; ++s) {
        const size_t qrow = base_q + (size_t)(q0 + s * 16 + lrow) * LDQKV + quad * 8;
        qf[s][0] = *(const bf16x8*)&QKV[qrow];
        qf[s][1] = *(const bf16x8*)&QKV[qrow + 32];
    }

    float l_part[2] = {0.f, 0.f};
    floatx4 o_acc[2][4];
#pragma unroll
    for (int s = 0; s < 2; ++s)
#pragma unroll
        for (int d = 0; d < 4; ++d) o_acc[s][d] = floatx4{0.f, 0.f, 0.f, 0.f};

    // staging assignments
    const int skey = t >> 2;                       // Ks: key 0..63
    const int sch  = t & 3;                        //     d-chunk 0..3
    const int kp   = t >> 3;                       // Vt: key pair 0..31
    const int sch8 = t & 7;                        //     d-chunk-of-8 0..7
    const int vcol = ((2 * kp) & 63) ^ (sch8 << 3);

    // ---- prologue: stage tile 0 into registers ----
    const size_t gk0 = base_k + (size_t)skey * LDQKV + sch * 8;
    const size_t gv0 = base_v + (size_t)(2 * kp) * LDQKV + sch8 * 8;
    bf16x8 kv0 = *(const bf16x8*)&QKV[gk0];
    bf16x8 kv1 = *(const bf16x8*)&QKV[gk0 + 32];
    bf16x8 vv0 = *(const bf16x8*)&QKV[gv0];
    bf16x8 vv1 = *(const bf16x8*)&QKV[gv0 + LDQKV];

    for (int k0 = 0; k0 < SEQ; k0 += 64) {
        // ---- write staged tile regs -> LDS ----
        *(bf16x8*)&Ks[skey * 72 + sch * 8]      = kv0;
        *(bf16x8*)&Ks[skey * 72 + sch * 8 + 32] = kv1;
#pragma unroll
        for (int j = 0; j < 8; ++j)
            *(bf16x2*)&Vt[(sch8 * 8 + j) * 72 + vcol] = bf16x2{vv0[j], vv1[j]};
        __syncthreads();

        // ---- prefetch next tile into regs (latency hides under compute) ----
        if (k0 + 64 < SEQ) {
            const size_t gk = gk0 + (size_t)(k0 + 64) * LDQKV;
            const size_t gv = gv0 + (size_t)(k0 + 64) * LDQKV;
            kv0 = *(const bf16x8*)&QKV[gk];
            kv1 = *(const bf16x8*)&QKV[gk + 32];
            vv0 = *(const bf16x8*)&QKV[gv];
            vv1 = *(const bf16x8*)&QKV[gv + LDQKV];
        }

        __builtin_amdgcn_s_setprio(1);
        // ---- S^T = K Q^T (k32), exp2 -> P kept in registers ----
        short4_t p[2][4];
#pragma unroll
        for (int kt = 0; kt < 4; ++kt) {
            bf16x8 ka0 = *(bf16x8*)&Ks[(kt * 16 + lrow) * 72 + quad * 8];
            bf16x8 ka1 = *(bf16x8*)&Ks[(kt * 16 + lrow) * 72 + 32 + quad * 8];
            floatx4 z = floatx4{0.f, 0.f, 0.f, 0.f};
#pragma unroll
            for (int s = 0; s < 2; ++s) {
                floatx4 st = __builtin_amdgcn_mfma_f32_16x16x32_bf16(ka0, qf[s][0], z, 0, 0, 0);
                st = __builtin_amdgcn_mfma_f32_16x16x32_bf16(ka1, qf[s][1], st, 0, 0, 0);
                float p0 = EXP2F(st[0]), p1 = EXP2F(st[1]);
                float p2 = EXP2F(st[2]), p3 = EXP2F(st[3]);
                l_part[s] += (p0 + p1) + (p2 + p3);
                bf16x4_cast pc;
                pc.h = bf16x4{(bf16_t)p0, (bf16_t)p1, (bf16_t)p2, (bf16_t)p3};
                p[s][kt] = pc.s;
            }
        }

        // ---- O^T += V^T P^T (k16): A = V^T b64 frag, B = P from registers --
#pragma unroll
        for (int dt = 0; dt < 4; ++dt) {
            const int d   = dt * 16 + lrow;
            const int swv = ((d >> 3) & 7) << 3;
#pragma unroll
            for (int kc = 0; kc < 4; ++kc) {
                bf16x4_cast ac;
                ac.h = *(bf16x4*)&Vt[d * 72 + ((kc * 16 + quad * 4) ^ swv)];
                o_acc[0][dt] = __builtin_amdgcn_mfma_f32_16x16x16bf16_1k(
                    ac.s, p[0][kc], o_acc[0][dt], 0, 0, 0);
                o_acc[1][dt] = __builtin_amdgcn_mfma_f32_16x16x16bf16_1k(
                    ac.s, p[1][kc], o_acc[1][dt], 0, 0, 0);
            }
        }
        __builtin_amdgcn_s_setprio(0);
        __syncthreads();   // protect Ks/Vt before next staging
    }

    // ---- reduce l across quads + normalize + packed b64 stores ----
    // O^T C-layout: lane holds q = lrow (matches l), d = 16dt + 4quad + r.
#pragma unroll
    for (int s = 0; s < 2; ++s) {
        float lsum = l_part[s];
        lsum += __shfl_xor(lsum, 16, 64);
        lsum += __shfl_xor(lsum, 32, 64);
        const float inv = 1.0f / lsum;
        const size_t orow = base_o + (size_t)(q0 + s * 16 + lrow) * D_MODEL;
#pragma unroll
        for (int dt = 0; dt < 4; ++dt) {
            bf16x4 ov = bf16x4{(bf16_t)(o_acc[s][dt][0] * inv),
                               (bf16_t)(o_acc[s][dt][1] * inv),
                               (bf16_t)(o_acc[s][dt][2] * inv),
                               (bf16_t)(o_acc[s][dt][3] * inv)};
            *(bf16x4*)&Ctx[orow + dt * 16 + quad * 4] = ov;
        }
    }
}

// --------------------------- residual + layernorm --------------------------
__global__ __launch_bounds__(256) void ln_res_f32in_kernel(
    const float* __restrict__ x, const bf16_t* __restrict__ res,
    const float* __restrict__ g, const float* __restrict__ be,
    bf16_t* __restrict__ out) {
    const int row = blockIdx.x, t = threadIdx.x;
    const size_t base = (size_t)row * D_MODEL;
    float vals[3], sum = 0.f, sq = 0.f;
#pragma unroll
    for (int it = 0; it < 3; ++it) {
        int i = t + it * 256;
        float v = x[base + i] + (float)res[base + i];
        vals[it] = v; sum += v; sq += v * v;
    }
#pragma unroll
    for (int d = 1; d < 64; d <<= 1) { sum += __shfl_xor(sum, d, 64); sq += __shfl_xor(sq, d, 64); }
    __shared__ float ssum[4], ssq[4], s_mu, s_rs;
    if ((t & 63) == 0) { ssum[t >> 6] = sum; ssq[t >> 6] = sq; }
    __syncthreads();
    if (t == 0) {
        float S = ssum[0] + ssum[1] + ssum[2] + ssum[3];
        float Qq = ssq[0] + ssq[1] + ssq[2] + ssq[3];
        float mu = S / D_MODEL;
        s_mu = mu;
        s_rs = rsqrtf(Qq / D_MODEL - mu * mu + 1e-5f);
    }
    __syncthreads();
    const float mu = s_mu, rs = s_rs;
#pragma unroll
    for (int it = 0; it < 3; ++it) {
        int i = t + it * 256;
        out[base + i] = (bf16_t)((vals[it] - mu) * rs * g[i] + be[i]);
    }
}

__global__ __launch_bounds__(256) void ln_res_final_kernel(
    const bf16_t* __restrict__ a, const bf16_t* __restrict__ bfb,
    const float* __restrict__ g, const float* __restrict__ be,
    float* __restrict__ out) {
    const int row = blockIdx.x, t = threadIdx.x;
    const size_t base = (size_t)row * D_MODEL;
    float vals[3], sum = 0.f, sq = 0.f;
#pragma unroll
    for (int it = 0; it < 3; ++it) {
        int i = t + it * 256;
        float v = (float)a[base + i] + (float)bfb[base + i];
        vals[it] = v; sum += v; sq += v * v;
    }
#pragma unroll
    for (int d = 1; d < 64; d <<= 1) { sum += __shfl_xor(sum, d, 64); sq += __shfl_xor(sq, d, 64); }
    __shared__ float ssum[4], ssq[4], s_mu, s_rs;
    if ((t & 63) == 0) { ssum[t >> 6] = sum; ssq[t >> 6] = sq; }
    __syncthreads();
    if (t == 0) {
        float S = ssum[0] + ssum[1] + ssum[2] + ssum[3];
        float Qq = ssq[0] + ssq[1] + ssq[2] + ssq[3];
        float mu = S / D_MODEL;
        s_mu = mu;
        s_rs = rsqrtf(Qq / D_MODEL - mu * mu + 1e-5f);
    }
    __syncthreads();
    const float mu = s_mu, rs = s_rs;
#pragma unroll
    for (int it = 0; it < 3; ++it) {
        int i = t + it * 256;
        out[base + i] = (vals[it] - mu) * rs * g[i] + be[i];
    }
}

// ------------------------------- launcher ----------------------------------
extern "C" void kernel_launch(void* const* d_in, const int* in_sizes, int n_in,
                              void* d_out, int out_size, void* d_ws, size_t ws_size,
                              hipStream_t stream) {
    const float* x    = (const float*)d_in[0];
    const float* wq   = (const float*)d_in[1];
    const float* bq   = (const float*)d_in[2];
    const float* wk   = (const float*)d_in[3];
    const float* bk   = (const float*)d_in[4];
    const float* wv   = (const float*)d_in[5];
    const float* bv   = (const float*)d_in[6];
    const float* wo   = (const float*)d_in[7];
    const float* bo   = (const float*)d_in[8];
    const float* w1   = (const float*)d_in[9];
    const float* b1   = (const float*)d_in[10];
    const float* w2   = (const float*)d_in[11];
    const float* b2   = (const float*)d_in[12];
    const float* g1   = (const float*)d_in[13];
    const float* be1  = (const float*)d_in[14];
    const float* g2   = (const float*)d_in[15];
    const float* be2  = (const float*)d_in[16];
    float* out = (float*)d_out;

    // ---- workspace layout (aliased; ~127.5 MB) ----
    char* ws = (char*)d_ws;
    const size_t SZ_XB   = (size_t)M_ROWS * D_MODEL * 2;
    const size_t SZ_QKV  = (size_t)M_ROWS * LDQKV * 2;
    const size_t SZ_CTX  = SZ_XB;
    const size_t SZ_H    = (size_t)M_ROWS * H_FF * 2;
    const size_t SZ_WQKV = (size_t)LDQKV * D_MODEL * 2;
    const size_t SZ_WO   = (size_t)D_MODEL * D_MODEL * 2;
    const size_t SZ_W1   = (size_t)H_FF * D_MODEL * 2;

    bf16_t* xb    = (bf16_t*)(ws);                    // also n1 after LN1
    bf16_t* qkvb  = (bf16_t*)(ws + SZ_XB);            // also mha out (reuse)
    bf16_t* ctxb  = (bf16_t*)(ws + SZ_XB + SZ_QKV);   // also ffn2 out (reuse)
    bf16_t* hb    = (bf16_t*)(ws + SZ_XB + SZ_QKV + SZ_CTX);
    char*   wsw   = ws + SZ_XB + SZ_QKV + SZ_CTX + SZ_H;
    bf16_t* wqkvb = (bf16_t*)(wsw);
    bf16_t* wob   = (bf16_t*)(wsw + SZ_WQKV);
    bf16_t* w1b   = (bf16_t*)(wsw + SZ_WQKV + SZ_WO);
    bf16_t* w2b   = (bf16_t*)(wsw + SZ_WQKV + SZ_WO + SZ_W1);
    float*  bqkv  = (float*)(wsw + SZ_WQKV + SZ_WO + 2 * SZ_W1);
    bf16_t* mhab  = qkvb;
    bf16_t* n1b   = xb;
    bf16_t* ffb   = ctxb;

    fused_convert_kernel<<<NCONV_V / 256 + 9, 256, 0, stream>>>(
        x, wq, wk, wv, wo, w1, w2, bq, bk, bv,
        xb, wqkvb, wob, w1b, w2b, bqkv);

    gemm_lds_kernel<128><<<dim3(LDQKV / 128, M_ROWS / 128), 256, 0, stream>>>(
        xb, wqkvb, bqkv, qkvb, M_ROWS, LDQKV, D_MODEL, 0);

    attn_kernel<<<dim3(SEQ / 128 * BATCH * N_HEADS), 256, 0, stream>>>(qkvb, ctxb);

    gemm_lds_kernel<64><<<dim3(D_MODEL / 64, M_ROWS / 128), 256, 0, stream>>>(
        ctxb, wob, bo, mhab, M_ROWS, D_MODEL, D_MODEL, 0);

    ln_res_f32in_kernel<<<M_ROWS, 256, 0, stream>>>(x, mhab, g1, be1, n1b);

    gemm_lds_kernel<128><<<dim3(H_FF / 128, M_ROWS / 128), 256, 0, stream>>>(
        n1b, w1b, b1, hb, M_ROWS, H_FF, D_MODEL, 1);

    gemm_lds_kernel<64><<<dim3(D_MODEL / 64, M_ROWS / 128), 256, 0, stream>>>(
        hb, w2b, b2, ffb, M_ROWS, D_MODEL, H_FF, 0);

    ln_res_final_kernel<<<M_ROWS, 256, 0, stream>>>(n1b, ffb, g2, be2, out);
}